// Round 7
// baseline (309.768 us; speedup 1.0000x reference)
//
#include <hip/hip_runtime.h>
#include <hip/hip_bf16.h>
#include <math.h>
#include <stdint.h>

// TokenBottleneck v7 — dbuf LDS + reg-prefetch + VALU/MFMA interleave.
#define BB 8
#define NN 8192
#define HH 1024
#define SS 256
#define KK 1024

// Finite in f32 AND bf16; strictly below any real score (see R3 post-mortem).
#define MASKED_SCORE (-1.0e38f)

typedef _Float16 half8 __attribute__((ext_vector_type(8)));
typedef float f32x4 __attribute__((ext_vector_type(4)));

// ---------------------------------------------------------------------------
// Prep: W' = gamma ⊙ w1 split to fp16 hi/lo in MFMA B-fragment order (see v6).
// ---------------------------------------------------------------------------
__global__ __launch_bounds__(256) void tbv7_prep(
    const float* __restrict__ gamma,
    const float* __restrict__ beta,
    const float* __restrict__ w1,
    const float* __restrict__ b1,
    _Float16* __restrict__ whT_sw,
    _Float16* __restrict__ wlT_sw,
    float* __restrict__ u,
    float* __restrict__ vb)
{
    const int s = blockIdx.x;
    const int tid = threadIdx.x;
    const int ctg = s >> 4;
    double ud = 0.0, vd = 0.0;
#pragma unroll
    for (int i = 0; i < 4; ++i) {
        const int k = tid * 4 + i;
        const float wv = gamma[k] * w1[(size_t)k * SS + s];
        const _Float16 hh = (_Float16)wv;
        const _Float16 hl = (_Float16)(wv - (float)hh);
        const size_t idx = ((size_t)(ctg * 32 + (k >> 5)) * 512)
                         + (((k >> 3) & 3) * 16 + (s & 15)) * 8 + (k & 7);
        whT_sw[idx] = hh;
        wlT_sw[idx] = hl;
        ud += (double)wv;
        vd += (double)beta[k] * (double)w1[(size_t)k * SS + s];
    }
#pragma unroll
    for (int off = 32; off; off >>= 1) {
        ud += __shfl_xor(ud, off, 64);
        vd += __shfl_xor(vd, off, 64);
    }
    __shared__ double su[4], sv[4];
    if ((tid & 63) == 0) { su[tid >> 6] = ud; sv[tid >> 6] = vd; }
    __syncthreads();
    if (tid == 0) {
        u[s]  = (float)(su[0] + su[1] + su[2] + su[3]);
        vb[s] = (float)(sv[0] + sv[1] + sv[2] + sv[3] + (double)b1[s]);
    }
}

// ---------------------------------------------------------------------------
// MFMA scorer, v7: 64 rows/block, 256 thr (4 waves). Double-buffered LDS
// A-tiles; ONE barrier per K-chunk; next-chunk global loads issued before the
// MFMA block; f32->fp16 convert + LDS write interleaved between MFMA halves
// (VALU co-issues with matrix pipe). Accumulation chain per acc identical to
// v5/v6 (hh -> lo*bh -> hh*bl, same k order).
// ---------------------------------------------------------------------------
__global__ __launch_bounds__(256) void tbv7_scorer(
    const float* __restrict__ tokens,
    const _Float16* __restrict__ whT_sw,
    const _Float16* __restrict__ wlT_sw,
    const float* __restrict__ u,
    const float* __restrict__ vb,
    const float* __restrict__ w2,
    const float* __restrict__ b2,
    const int* __restrict__ mask,
    float* __restrict__ scores_out)
{
    __shared__ _Float16 Ah[2][64 * 128];
    __shared__ _Float16 Al[2][64 * 128];
    __shared__ float rs_s[64], m2_s[64];
    __shared__ double pl[4][64];

    const int tid  = threadIdx.x;
    const int lane = tid & 63;
    const int wv_  = tid >> 6;
    const int r0   = blockIdx.x * 64;

    const int srow  = tid >> 2;          // 4 threads per row
    const int scolf = (tid & 3) * 32;    // 32 consecutive floats each
    const float* srcbase = tokens + (size_t)(r0 + srow) * HH + scolf;

    double s_acc = 0.0, ss_acc = 0.0;

    f32x4 acc[4][4];
#pragma unroll
    for (int rt = 0; rt < 4; ++rt)
#pragma unroll
        for (int ct = 0; ct < 4; ++ct) acc[rt][ct] = (f32x4){0.f, 0.f, 0.f, 0.f};

    const int arow = lane & 15;
    const int kgrp = (lane >> 4) * 8;
    const int swz  = (srow & 7) << 3;

    // convert 32 staged floats -> fp16 hi/lo, accumulate LN stats, store LDS
    auto convert_store = [&](const float4* rr, int buf) {
        half8 hh[4], hl[4];
#pragma unroll
        for (int jj = 0; jj < 8; ++jj) {
            const float4 v = rr[jj];
#pragma unroll
            for (int e = 0; e < 4; ++e) {
                const float x = (e == 0) ? v.x : (e == 1) ? v.y : (e == 2) ? v.z : v.w;
                const int j = jj * 4 + e;
                s_acc  += (double)x;
                ss_acc += (double)x * (double)x;
                const _Float16 h = (_Float16)x;
                hh[j >> 3][j & 7] = h;
                hl[j >> 3][j & 7] = (_Float16)(x - (float)h);
            }
        }
#pragma unroll
        for (int j = 0; j < 4; ++j) {
            const int idx = srow * 128 + ((scolf + j * 8) ^ swz);
            *reinterpret_cast<half8*>(&Ah[buf][idx]) = hh[j];
            *reinterpret_cast<half8*>(&Al[buf][idx]) = hl[j];
        }
    };

    // one K=32 MFMA step on LDS buffer `buf`, absolute chunk c
    auto do_kstep = [&](int buf, int c, int k0) {
        half8 ah[4], al[4];
#pragma unroll
        for (int rt = 0; rt < 4; ++rt) {
            const int row = rt * 16 + arow;
            const int idx = row * 128 + ((k0 * 32 + kgrp) ^ ((row & 7) << 3));
            ah[rt] = *reinterpret_cast<const half8*>(&Ah[buf][idx]);
            al[rt] = *reinterpret_cast<const half8*>(&Al[buf][idx]);
        }
        half8 bh[4], bl[4];
#pragma unroll
        for (int ct = 0; ct < 4; ++ct) {
            const size_t base = ((size_t)((wv_ * 4 + ct) * 32 + c * 4 + k0) * 512)
                              + lane * 8;
            bh[ct] = *reinterpret_cast<const half8*>(&whT_sw[base]);
            bl[ct] = *reinterpret_cast<const half8*>(&wlT_sw[base]);
        }
#pragma unroll
        for (int ct = 0; ct < 4; ++ct)
#pragma unroll
            for (int rt = 0; rt < 4; ++rt)
                acc[rt][ct] = __builtin_amdgcn_mfma_f32_16x16x32_f16(
                    ah[rt], bh[ct], acc[rt][ct], 0, 0, 0);
#pragma unroll
        for (int ct = 0; ct < 4; ++ct)
#pragma unroll
            for (int rt = 0; rt < 4; ++rt)
                acc[rt][ct] = __builtin_amdgcn_mfma_f32_16x16x32_f16(
                    al[rt], bh[ct], acc[rt][ct], 0, 0, 0);
#pragma unroll
        for (int ct = 0; ct < 4; ++ct)
#pragma unroll
            for (int rt = 0; rt < 4; ++rt)
                acc[rt][ct] = __builtin_amdgcn_mfma_f32_16x16x32_f16(
                    ah[rt], bl[ct], acc[rt][ct], 0, 0, 0);
    };

    // prologue: stage chunk 0 into buf 0
    {
        float4 r[8];
#pragma unroll
        for (int j = 0; j < 8; ++j)
            r[j] = *reinterpret_cast<const float4*>(srcbase + j * 4);
        convert_store(r, 0);
    }
    __syncthreads();

    for (int c = 0; c < 8; ++c) {
        const int cur = c & 1;
        float4 r2[8];
        if (c < 7) {
            const float* s2 = srcbase + (c + 1) * 128;
#pragma unroll
            for (int j = 0; j < 8; ++j)
                r2[j] = *reinterpret_cast<const float4*>(s2 + j * 4);
        }
        do_kstep(cur, c, 0);
        do_kstep(cur, c, 1);
        if (c < 7) convert_store(r2, cur ^ 1);   // writes OTHER buffer
        do_kstep(cur, c, 2);
        do_kstep(cur, c, 3);
        __syncthreads();   // readers of buf[cur] done; buf[cur^1] published
    }

    // ---- LN stats finalize: 4 threads per row ----
#pragma unroll
    for (int off = 2; off; off >>= 1) {
        s_acc  += __shfl_xor(s_acc, off, 64);
        ss_acc += __shfl_xor(ss_acc, off, 64);
    }
    if ((tid & 3) == 0) {
        const double mu  = s_acc * (1.0 / HH);
        const double var = ss_acc * (1.0 / HH) - mu * mu;
        const double rs  = 1.0 / sqrt(var + 1e-5);
        rs_s[srow] = (float)rs;
        m2_s[srow] = (float)(-mu * rs);
    }
    __syncthreads();

    // ---- epilogue: h = rs*G + m2*u + vb; relu; dot w2 (fp64) ----
    double p[4][4] = {{0,0,0,0},{0,0,0,0},{0,0,0,0},{0,0,0,0}};
#pragma unroll
    for (int ct = 0; ct < 4; ++ct) {
        const int col = wv_ * 64 + ct * 16 + arow;
        const double uc  = (double)u[col];
        const double vbc = (double)vb[col];
        const double w2c = (double)w2[col];
#pragma unroll
        for (int rt = 0; rt < 4; ++rt)
#pragma unroll
            for (int q = 0; q < 4; ++q) {
                const int row = rt * 16 + (lane >> 4) * 4 + q;
                const double h = (double)rs_s[row] * (double)acc[rt][ct][q]
                               + (double)m2_s[row] * uc + vbc;
                p[rt][q] += (h > 0.0 ? h : 0.0) * w2c;
            }
    }
#pragma unroll
    for (int off = 8; off; off >>= 1)
#pragma unroll
        for (int rt = 0; rt < 4; ++rt)
#pragma unroll
            for (int q = 0; q < 4; ++q)
                p[rt][q] += __shfl_xor(p[rt][q], off, 64);
    if ((lane & 15) == 0)
#pragma unroll
        for (int rt = 0; rt < 4; ++rt)
#pragma unroll
            for (int q = 0; q < 4; ++q)
                pl[wv_][rt * 16 + (lane >> 4) * 4 + q] = p[rt][q];
    __syncthreads();

    if (tid < 64) {
        const size_t tok = (size_t)r0 + tid;
        float scf = (float)(pl[0][tid] + pl[1][tid] + pl[2][tid] + pl[3][tid]
                            + (double)b2[0]);
        if (mask[tok] == 0) scf = MASKED_SCORE;
        scores_out[tok] = scf;
    }
}

// ---------------------------------------------------------------------------
// Fallback fp64 scorer (only if ws too small for W' tables).
// ---------------------------------------------------------------------------
__global__ __launch_bounds__(256) void tbv7_scorer_fp64(
    const float* __restrict__ tokens,
    const float* __restrict__ gamma,
    const float* __restrict__ beta,
    const float* __restrict__ w1,
    const float* __restrict__ b1,
    const float* __restrict__ w2,
    const float* __restrict__ b2,
    const int* __restrict__ mask,
    float* __restrict__ scores_out)
{
    __shared__ float xs[16][HH];
    const int tid = threadIdx.x;
    const size_t tok0 = (size_t)blockIdx.x * 16;
    {
        const float4* src = reinterpret_cast<const float4*>(tokens + tok0 * HH);
        float4* dst = reinterpret_cast<float4*>(&xs[0][0]);
#pragma unroll
        for (int i = 0; i < (16 * HH / 4) / 256; ++i)
            dst[tid + i * 256] = src[tid + i * 256];
    }
    __syncthreads();
    {
        const int row = tid >> 4, l16 = tid & 15;
        double s = 0.0, ss = 0.0;
        for (int h = l16; h < HH; h += 16) {
            const double v = (double)xs[row][h];
            s += v; ss += v * v;
        }
#pragma unroll
        for (int off = 8; off; off >>= 1) {
            s += __shfl_xor(s, off, 64); ss += __shfl_xor(ss, off, 64);
        }
        const double mu = s / HH, var = ss / HH - mu * mu;
        const double rs = 1.0 / sqrt(var + 1e-5);
        for (int h = l16; h < HH; h += 16)
            xs[row][h] = (float)(((double)xs[row][h] - mu) * rs * (double)gamma[h]
                                 + (double)beta[h]);
    }
    __syncthreads();
    const int lane = tid & 63, wv_ = tid >> 6;
    double acc[4][4];
#pragma unroll
    for (int i = 0; i < 4; ++i)
#pragma unroll
        for (int c = 0; c < 4; ++c) acc[i][c] = 0.0;
    for (int h = 0; h < HH; ++h) {
        const float w0 = w1[(size_t)h * SS + lane];
        const float wc1 = w1[(size_t)h * SS + 64 + lane];
        const float wc2 = w1[(size_t)h * SS + 128 + lane];
        const float wc3 = w1[(size_t)h * SS + 192 + lane];
#pragma unroll
        for (int ii = 0; ii < 4; ++ii) {
            const double x0 = (double)xs[wv_ * 4 + ii][h];
            acc[ii][0] += x0 * (double)w0;  acc[ii][1] += x0 * (double)wc1;
            acc[ii][2] += x0 * (double)wc2; acc[ii][3] += x0 * (double)wc3;
        }
    }
    const double b2v = (double)b2[0];
#pragma unroll
    for (int ii = 0; ii < 4; ++ii) {
        double p = 0.0;
#pragma unroll
        for (int c = 0; c < 4; ++c) {
            const int scol = c * 64 + lane;
            double hv = acc[ii][c] + (double)b1[scol];
            hv = hv > 0.0 ? hv : 0.0;
            p += hv * (double)w2[scol];
        }
#pragma unroll
        for (int off = 32; off; off >>= 1) p += __shfl_xor(p, off, 64);
        if (lane == 0) {
            const size_t tok = tok0 + (size_t)wv_ * 4 + ii;
            float scf = (float)(p + b2v);
            if (mask[tok] == 0) scf = MASKED_SCORE;
            scores_out[tok] = scf;
        }
    }
}

// ---------------------------------------------------------------------------
// Top-k: per-batch bitonic sort of composite keys.
// ---------------------------------------------------------------------------
__global__ __launch_bounds__(1024) void tbv7_topk(
    const float* __restrict__ scores,
    const int* __restrict__ mask,
    float* __restrict__ idx_out,
    float* __restrict__ selmask_out)
{
    __shared__ unsigned long long k[NN];
    const int b = blockIdx.x, tid = threadIdx.x;
    for (int i = tid; i < NN; i += 1024) {
        const unsigned int uu = __float_as_uint(scores[(size_t)b * NN + i]);
        const unsigned int ord = (uu & 0x80000000u) ? ~uu : (uu | 0x80000000u);
        k[i] = ((unsigned long long)ord << 32) |
               (unsigned long long)(unsigned int)(NN - 1 - i);
    }
    __syncthreads();
    for (int kk = 2; kk <= NN; kk <<= 1) {
        for (int j = kk >> 1; j > 0; j >>= 1) {
            for (int p = tid; p < NN / 2; p += 1024) {
                const int i1 = 2 * p - (p & (j - 1));
                const int i2 = i1 + j;
                const unsigned long long a = k[i1], c = k[i2];
                const bool up = (i1 & kk) != 0;
                const bool sw = up ? (a > c) : (a < c);
                if (sw) { k[i1] = c; k[i2] = a; }
            }
            __syncthreads();
        }
    }
    for (int j = tid; j < KK; j += 1024) {
        const int n = (NN - 1) - (int)(k[j] & 0xFFFFFFFFull);
        const int m = mask[(size_t)b * NN + n] ? 1 : 0;
        idx_out[(size_t)b * KK + j]     = (float)n;
        selmask_out[(size_t)b * KK + j] = (float)m;
    }
}

// ---------------------------------------------------------------------------
// Gather.
// ---------------------------------------------------------------------------
__global__ __launch_bounds__(256) void tbv7_gather(
    const float* __restrict__ tokens,
    const float* __restrict__ idx_out,
    const int* __restrict__ mask,
    float* __restrict__ gathered)
{
    const int bj = blockIdx.x;
    const int b  = bj >> 10;
    const int n  = (int)idx_out[bj];
    const int m  = mask[(size_t)b * NN + n];
    const float4* src = reinterpret_cast<const float4*>(tokens + ((size_t)b * NN + n) * HH);
    float4* dst = reinterpret_cast<float4*>(gathered + (size_t)bj * HH);
    float4 v = src[threadIdx.x];
    if (!m) v = make_float4(0.f, 0.f, 0.f, 0.f);
    dst[threadIdx.x] = v;
}

// ---------------------------------------------------------------------------
extern "C" void kernel_launch(void* const* d_in, const int* in_sizes, int n_in,
                              void* d_out, int out_size, void* d_ws, size_t ws_size,
                              hipStream_t stream)
{
    const float* tokens = (const float*)d_in[0];
    const float* gamma  = (const float*)d_in[1];
    const float* beta   = (const float*)d_in[2];
    const float* w1     = (const float*)d_in[3];
    const float* b1     = (const float*)d_in[4];
    const float* w2     = (const float*)d_in[5];
    const float* b2     = (const float*)d_in[6];
    const int*   mask   = (const int*)d_in[7];

    float* out      = (float*)d_out;
    float* gathered = out;                                   // B*K*H
    float* idx_out  = out + (size_t)BB * KK * HH;            // B*K
    float* scores   = idx_out + (size_t)BB * KK;             // B*N
    float* selmask  = scores + (size_t)BB * NN;              // B*K

    const size_t whT_bytes = (size_t)SS * HH * sizeof(_Float16);   // 512KB
    const size_t need = 2 * whT_bytes + 2 * SS * sizeof(float);

    if (ws_size >= need) {
        _Float16* whT_sw = (_Float16*)d_ws;
        _Float16* wlT_sw = (_Float16*)((char*)d_ws + whT_bytes);
        float* u  = (float*)((char*)d_ws + 2 * whT_bytes);
        float* vbp = u + SS;
        hipLaunchKernelGGL(tbv7_prep, dim3(SS), dim3(256), 0, stream,
                           gamma, beta, w1, b1, whT_sw, wlT_sw, u, vbp);
        hipLaunchKernelGGL(tbv7_scorer, dim3(BB * NN / 64), dim3(256), 0, stream,
                           tokens, whT_sw, wlT_sw, u, vbp, w2, b2, mask, scores);
    } else {
        hipLaunchKernelGGL(tbv7_scorer_fp64, dim3(BB * NN / 16), dim3(256), 0, stream,
                           tokens, gamma, beta, w1, b1, w2, b2, mask, scores);
    }
    hipLaunchKernelGGL(tbv7_topk, dim3(BB), dim3(1024), 0, stream,
                       scores, mask, idx_out, selmask);
    hipLaunchKernelGGL(tbv7_gather, dim3(BB * KK), dim3(256), 0, stream,
                       tokens, idx_out, mask, gathered);
}

// Round 8
// 240.530 us; speedup vs baseline: 1.2879x; 1.2879x over previous
//
#include <hip/hip_runtime.h>
#include <hip/hip_bf16.h>
#include <math.h>
#include <stdint.h>

// TokenBottleneck v8 — BM=256 / 512-thread / 1 block per CU MFMA scorer.
#define BB 8
#define NN 8192
#define HH 1024
#define SS 256
#define KK 1024

// Finite in f32 AND bf16; strictly below any real score (see R3 post-mortem).
#define MASKED_SCORE (-1.0e38f)

typedef _Float16 half8 __attribute__((ext_vector_type(8)));
typedef float f32x4 __attribute__((ext_vector_type(4)));

// ---------------------------------------------------------------------------
// Prep: W' = gamma ⊙ w1 split to fp16 hi/lo in MFMA B-fragment order:
// element (s,k) -> [(colgrp*32 + ks)*512 + lane*8 + j], colgrp=s>>4, ks=k>>5,
// lane=((k>>3)&3)*16 + (s&15), j=k&7. u[s]=Σ γ w1; vb[s]=Σ β w1 + b1.
// ---------------------------------------------------------------------------
__global__ __launch_bounds__(256) void tbv8_prep(
    const float* __restrict__ gamma,
    const float* __restrict__ beta,
    const float* __restrict__ w1,
    const float* __restrict__ b1,
    _Float16* __restrict__ whT_sw,
    _Float16* __restrict__ wlT_sw,
    float* __restrict__ u,
    float* __restrict__ vb)
{
    const int s = blockIdx.x;
    const int tid = threadIdx.x;
    const int ctg = s >> 4;
    double ud = 0.0, vd = 0.0;
#pragma unroll
    for (int i = 0; i < 4; ++i) {
        const int k = tid * 4 + i;
        const float wv = gamma[k] * w1[(size_t)k * SS + s];
        const _Float16 hh = (_Float16)wv;
        const _Float16 hl = (_Float16)(wv - (float)hh);
        const size_t idx = ((size_t)(ctg * 32 + (k >> 5)) * 512)
                         + (((k >> 3) & 3) * 16 + (s & 15)) * 8 + (k & 7);
        whT_sw[idx] = hh;
        wlT_sw[idx] = hl;
        ud += (double)wv;
        vd += (double)beta[k] * (double)w1[(size_t)k * SS + s];
    }
#pragma unroll
    for (int off = 32; off; off >>= 1) {
        ud += __shfl_xor(ud, off, 64);
        vd += __shfl_xor(vd, off, 64);
    }
    __shared__ double su[4], sv[4];
    if ((tid & 63) == 0) { su[tid >> 6] = ud; sv[tid >> 6] = vd; }
    __syncthreads();
    if (tid == 0) {
        u[s]  = (float)(su[0] + su[1] + su[2] + su[3]);
        vb[s] = (float)(sv[0] + sv[1] + sv[2] + sv[3] + (double)b1[s]);
    }
}

// ---------------------------------------------------------------------------
// v8 scorer: 256 rows/block, 512 thr (8 waves as 2 row-halves x 4 col-quads).
// BK=64 double-buffered LDS (fp16 hi/lo of raw tokens, XOR-swizzled).
// Grid = 256 = 1 block/CU. LN folded via (u, vb, mu, rs). Per-acc chain
// identical to v5-v7: ah·bh -> al·bh -> ah·bl, k ascending.
// ---------------------------------------------------------------------------
__global__ __launch_bounds__(512, 2) void tbv8_scorer(
    const float* __restrict__ tokens,
    const _Float16* __restrict__ whT_sw,
    const _Float16* __restrict__ wlT_sw,
    const float* __restrict__ u,
    const float* __restrict__ vb,
    const float* __restrict__ w2,
    const float* __restrict__ b2,
    const int* __restrict__ mask,
    float* __restrict__ scores_out)
{
    __shared__ _Float16 Ah[2][256 * 64];
    __shared__ _Float16 Al[2][256 * 64];
    __shared__ float rs_s[256], m2_s[256];
    __shared__ double pl[4][256];

    const int tid  = threadIdx.x;
    const int lane = tid & 63;
    const int wid  = tid >> 6;
    const int wr   = wid >> 2;          // row-half 0/1
    const int wc   = wid & 3;           // col-quad 0..3
    const int r0   = blockIdx.x * 256;

    const int srow  = tid >> 1;         // 2 threads per row
    const int scolf = (tid & 1) * 32;   // 32 consecutive floats each
    const float* srcbase = tokens + (size_t)(r0 + srow) * HH + scolf;

    double s_acc = 0.0, ss_acc = 0.0;

    f32x4 acc[8][4];
#pragma unroll
    for (int rt = 0; rt < 8; ++rt)
#pragma unroll
        for (int ct = 0; ct < 4; ++ct) acc[rt][ct] = (f32x4){0.f, 0.f, 0.f, 0.f};

    const int arow = lane & 15;
    const int kgrp = (lane >> 4) * 8;
    const int swz  = (srow & 7) << 3;

    // convert 32 staged floats -> fp16 hi/lo + LN stats + swizzled LDS store
    auto convert_store = [&](const float4* rr, int buf) {
        half8 hh[4], hl[4];
#pragma unroll
        for (int jj = 0; jj < 8; ++jj) {
            const float4 v = rr[jj];
#pragma unroll
            for (int e = 0; e < 4; ++e) {
                const float x = (e == 0) ? v.x : (e == 1) ? v.y : (e == 2) ? v.z : v.w;
                const int j = jj * 4 + e;
                s_acc  += (double)x;
                ss_acc += (double)x * (double)x;
                const _Float16 h = (_Float16)x;
                hh[j >> 3][j & 7] = h;
                hl[j >> 3][j & 7] = (_Float16)(x - (float)h);
            }
        }
#pragma unroll
        for (int j = 0; j < 4; ++j) {
            const int idx = srow * 64 + ((scolf + j * 8) ^ swz);
            *reinterpret_cast<half8*>(&Ah[buf][idx]) = hh[j];
            *reinterpret_cast<half8*>(&Al[buf][idx]) = hl[j];
        }
    };

    // one K=32 MFMA step; A-frags streamed per rt (low register pressure)
    auto do_kstep = [&](int buf, int c, int k0) {
        half8 bh[4], bl[4];
#pragma unroll
        for (int ct = 0; ct < 4; ++ct) {
            const size_t base = ((size_t)((wc * 4 + ct) * 32 + c * 2 + k0) * 512)
                              + lane * 8;
            bh[ct] = *reinterpret_cast<const half8*>(&whT_sw[base]);
            bl[ct] = *reinterpret_cast<const half8*>(&wlT_sw[base]);
        }
#pragma unroll
        for (int rt = 0; rt < 8; ++rt) {
            const int row = wr * 128 + rt * 16 + arow;
            const int idx = row * 64 + ((k0 * 32 + kgrp) ^ ((row & 7) << 3));
            const half8 ah = *reinterpret_cast<const half8*>(&Ah[buf][idx]);
            const half8 al = *reinterpret_cast<const half8*>(&Al[buf][idx]);
#pragma unroll
            for (int ct = 0; ct < 4; ++ct)
                acc[rt][ct] = __builtin_amdgcn_mfma_f32_16x16x32_f16(
                    ah, bh[ct], acc[rt][ct], 0, 0, 0);
#pragma unroll
            for (int ct = 0; ct < 4; ++ct)
                acc[rt][ct] = __builtin_amdgcn_mfma_f32_16x16x32_f16(
                    al, bh[ct], acc[rt][ct], 0, 0, 0);
#pragma unroll
            for (int ct = 0; ct < 4; ++ct)
                acc[rt][ct] = __builtin_amdgcn_mfma_f32_16x16x32_f16(
                    ah, bl[ct], acc[rt][ct], 0, 0, 0);
        }
    };

    // prologue: stage chunk 0 into buf 0
    {
        float4 r[8];
#pragma unroll
        for (int j = 0; j < 8; ++j)
            r[j] = *reinterpret_cast<const float4*>(srcbase + j * 4);
        convert_store(r, 0);
    }
    __syncthreads();

    for (int c = 0; c < 16; ++c) {
        const int cur = c & 1;
        float4 r2[8];
        if (c < 15) {
            const float* s2 = srcbase + (c + 1) * 64;
#pragma unroll
            for (int j = 0; j < 8; ++j)
                r2[j] = *reinterpret_cast<const float4*>(s2 + j * 4);
        }
        do_kstep(cur, c, 0);
        if (c < 15) convert_store(r2, cur ^ 1);   // writes OTHER buffer
        do_kstep(cur, c, 1);
        __syncthreads();
    }

    // ---- LN stats finalize (2 threads per row) ----
    s_acc  += __shfl_xor(s_acc, 1, 64);
    ss_acc += __shfl_xor(ss_acc, 1, 64);
    if ((tid & 1) == 0) {
        const double mu  = s_acc * (1.0 / HH);
        const double var = ss_acc * (1.0 / HH) - mu * mu;
        const double rs  = 1.0 / sqrt(var + 1e-5);
        rs_s[srow] = (float)rs;
        m2_s[srow] = (float)(-mu * rs);
    }
    __syncthreads();

    // ---- epilogue: h = rs*G + m2*u + vb; relu; dot w2 ----
    double p[8][4];
#pragma unroll
    for (int rt = 0; rt < 8; ++rt)
#pragma unroll
        for (int q = 0; q < 4; ++q) p[rt][q] = 0.0;
#pragma unroll
    for (int ct = 0; ct < 4; ++ct) {
        const int col = wc * 64 + ct * 16 + arow;
        const double uc  = (double)u[col];
        const double vbc = (double)vb[col];
        const double w2c = (double)w2[col];
#pragma unroll
        for (int rt = 0; rt < 8; ++rt)
#pragma unroll
            for (int q = 0; q < 4; ++q) {
                const int row = wr * 128 + rt * 16 + (lane >> 4) * 4 + q;
                const double h = (double)rs_s[row] * (double)acc[rt][ct][q]
                               + (double)m2_s[row] * uc + vbc;
                p[rt][q] += (h > 0.0 ? h : 0.0) * w2c;
            }
    }
#pragma unroll
    for (int off = 8; off; off >>= 1)
#pragma unroll
        for (int rt = 0; rt < 8; ++rt)
#pragma unroll
            for (int q = 0; q < 4; ++q)
                p[rt][q] += __shfl_xor(p[rt][q], off, 64);
    if ((lane & 15) == 0)
#pragma unroll
        for (int rt = 0; rt < 8; ++rt)
#pragma unroll
            for (int q = 0; q < 4; ++q)
                pl[wc][wr * 128 + rt * 16 + (lane >> 4) * 4 + q] = p[rt][q];
    __syncthreads();

    if (tid < 256) {
        const size_t tok = (size_t)r0 + tid;
        float scf = (float)(pl[0][tid] + pl[1][tid] + pl[2][tid] + pl[3][tid]
                            + (double)b2[0]);
        if (mask[tok] == 0) scf = MASKED_SCORE;
        scores_out[tok] = scf;
    }
}

// ---------------------------------------------------------------------------
// Fallback fp64 scorer (only if ws too small for W' tables).
// ---------------------------------------------------------------------------
__global__ __launch_bounds__(256) void tbv8_scorer_fp64(
    const float* __restrict__ tokens,
    const float* __restrict__ gamma,
    const float* __restrict__ beta,
    const float* __restrict__ w1,
    const float* __restrict__ b1,
    const float* __restrict__ w2,
    const float* __restrict__ b2,
    const int* __restrict__ mask,
    float* __restrict__ scores_out)
{
    __shared__ float xs[16][HH];
    const int tid = threadIdx.x;
    const size_t tok0 = (size_t)blockIdx.x * 16;
    {
        const float4* src = reinterpret_cast<const float4*>(tokens + tok0 * HH);
        float4* dst = reinterpret_cast<float4*>(&xs[0][0]);
#pragma unroll
        for (int i = 0; i < (16 * HH / 4) / 256; ++i)
            dst[tid + i * 256] = src[tid + i * 256];
    }
    __syncthreads();
    {
        const int row = tid >> 4, l16 = tid & 15;
        double s = 0.0, ss = 0.0;
        for (int h = l16; h < HH; h += 16) {
            const double v = (double)xs[row][h];
            s += v; ss += v * v;
        }
#pragma unroll
        for (int off = 8; off; off >>= 1) {
            s += __shfl_xor(s, off, 64); ss += __shfl_xor(ss, off, 64);
        }
        const double mu = s / HH, var = ss / HH - mu * mu;
        const double rs = 1.0 / sqrt(var + 1e-5);
        for (int h = l16; h < HH; h += 16)
            xs[row][h] = (float)(((double)xs[row][h] - mu) * rs * (double)gamma[h]
                                 + (double)beta[h]);
    }
    __syncthreads();
    const int lane = tid & 63, wv_ = tid >> 6;
    double acc[4][4];
#pragma unroll
    for (int i = 0; i < 4; ++i)
#pragma unroll
        for (int c = 0; c < 4; ++c) acc[i][c] = 0.0;
    for (int h = 0; h < HH; ++h) {
        const float w0 = w1[(size_t)h * SS + lane];
        const float wc1 = w1[(size_t)h * SS + 64 + lane];
        const float wc2 = w1[(size_t)h * SS + 128 + lane];
        const float wc3 = w1[(size_t)h * SS + 192 + lane];
#pragma unroll
        for (int ii = 0; ii < 4; ++ii) {
            const double x0 = (double)xs[wv_ * 4 + ii][h];
            acc[ii][0] += x0 * (double)w0;  acc[ii][1] += x0 * (double)wc1;
            acc[ii][2] += x0 * (double)wc2; acc[ii][3] += x0 * (double)wc3;
        }
    }
    const double b2v = (double)b2[0];
#pragma unroll
    for (int ii = 0; ii < 4; ++ii) {
        double p = 0.0;
#pragma unroll
        for (int c = 0; c < 4; ++c) {
            const int scol = c * 64 + lane;
            double hv = acc[ii][c] + (double)b1[scol];
            hv = hv > 0.0 ? hv : 0.0;
            p += hv * (double)w2[scol];
        }
#pragma unroll
        for (int off = 32; off; off >>= 1) p += __shfl_xor(p, off, 64);
        if (lane == 0) {
            const size_t tok = tok0 + (size_t)wv_ * 4 + ii;
            float scf = (float)(p + b2v);
            if (mask[tok] == 0) scf = MASKED_SCORE;
            scores_out[tok] = scf;
        }
    }
}

// ---------------------------------------------------------------------------
// Top-k: per-batch bitonic sort of composite keys.
// ---------------------------------------------------------------------------
__global__ __launch_bounds__(1024) void tbv8_topk(
    const float* __restrict__ scores,
    const int* __restrict__ mask,
    float* __restrict__ idx_out,
    float* __restrict__ selmask_out)
{
    __shared__ unsigned long long k[NN];
    const int b = blockIdx.x, tid = threadIdx.x;
    for (int i = tid; i < NN; i += 1024) {
        const unsigned int uu = __float_as_uint(scores[(size_t)b * NN + i]);
        const unsigned int ord = (uu & 0x80000000u) ? ~uu : (uu | 0x80000000u);
        k[i] = ((unsigned long long)ord << 32) |
               (unsigned long long)(unsigned int)(NN - 1 - i);
    }
    __syncthreads();
    for (int kk = 2; kk <= NN; kk <<= 1) {
        for (int j = kk >> 1; j > 0; j >>= 1) {
            for (int p = tid; p < NN / 2; p += 1024) {
                const int i1 = 2 * p - (p & (j - 1));
                const int i2 = i1 + j;
                const unsigned long long a = k[i1], c = k[i2];
                const bool up = (i1 & kk) != 0;
                const bool sw = up ? (a > c) : (a < c);
                if (sw) { k[i1] = c; k[i2] = a; }
            }
            __syncthreads();
        }
    }
    for (int j = tid; j < KK; j += 1024) {
        const int n = (NN - 1) - (int)(k[j] & 0xFFFFFFFFull);
        const int m = mask[(size_t)b * NN + n] ? 1 : 0;
        idx_out[(size_t)b * KK + j]     = (float)n;
        selmask_out[(size_t)b * KK + j] = (float)m;
    }
}

// ---------------------------------------------------------------------------
// Gather.
// ---------------------------------------------------------------------------
__global__ __launch_bounds__(256) void tbv8_gather(
    const float* __restrict__ tokens,
    const float* __restrict__ idx_out,
    const int* __restrict__ mask,
    float* __restrict__ gathered)
{
    const int bj = blockIdx.x;
    const int b  = bj >> 10;
    const int n  = (int)idx_out[bj];
    const int m  = mask[(size_t)b * NN + n];
    const float4* src = reinterpret_cast<const float4*>(tokens + ((size_t)b * NN + n) * HH);
    float4* dst = reinterpret_cast<float4*>(gathered + (size_t)bj * HH);
    float4 v = src[threadIdx.x];
    if (!m) v = make_float4(0.f, 0.f, 0.f, 0.f);
    dst[threadIdx.x] = v;
}

// ---------------------------------------------------------------------------
extern "C" void kernel_launch(void* const* d_in, const int* in_sizes, int n_in,
                              void* d_out, int out_size, void* d_ws, size_t ws_size,
                              hipStream_t stream)
{
    const float* tokens = (const float*)d_in[0];
    const float* gamma  = (const float*)d_in[1];
    const float* beta   = (const float*)d_in[2];
    const float* w1     = (const float*)d_in[3];
    const float* b1     = (const float*)d_in[4];
    const float* w2     = (const float*)d_in[5];
    const float* b2     = (const float*)d_in[6];
    const int*   mask   = (const int*)d_in[7];

    float* out      = (float*)d_out;
    float* gathered = out;                                   // B*K*H
    float* idx_out  = out + (size_t)BB * KK * HH;            // B*K
    float* scores   = idx_out + (size_t)BB * KK;             // B*N
    float* selmask  = scores + (size_t)BB * NN;              // B*K

    const size_t whT_bytes = (size_t)SS * HH * sizeof(_Float16);   // 512KB
    const size_t need = 2 * whT_bytes + 2 * SS * sizeof(float);

    if (ws_size >= need) {
        _Float16* whT_sw = (_Float16*)d_ws;
        _Float16* wlT_sw = (_Float16*)((char*)d_ws + whT_bytes);
        float* u  = (float*)((char*)d_ws + 2 * whT_bytes);
        float* vbp = u + SS;
        hipLaunchKernelGGL(tbv8_prep, dim3(SS), dim3(256), 0, stream,
                           gamma, beta, w1, b1, whT_sw, wlT_sw, u, vbp);
        hipLaunchKernelGGL(tbv8_scorer, dim3(BB * NN / 256), dim3(512), 0, stream,
                           tokens, whT_sw, wlT_sw, u, vbp, w2, b2, mask, scores);
    } else {
        hipLaunchKernelGGL(tbv8_scorer_fp64, dim3(BB * NN / 16), dim3(256), 0, stream,
                           tokens, gamma, beta, w1, b1, w2, b2, mask, scores);
    }
    hipLaunchKernelGGL(tbv8_topk, dim3(BB), dim3(1024), 0, stream,
                       scores, mask, idx_out, selmask);
    hipLaunchKernelGGL(tbv8_gather, dim3(BB * KK), dim3(256), 0, stream,
                       tokens, idx_out, mask, gathered);
}

// Round 9
// 207.084 us; speedup vs baseline: 1.4959x; 1.1615x over previous
//
#include <hip/hip_runtime.h>
#include <hip/hip_bf16.h>
#include <math.h>
#include <stdint.h>

// TokenBottleneck v9 — v8 + per-block K-chunk stagger (HBM channel spread)
//                      + fp32 epilogue (kill scratch spill).
#define BB 8
#define NN 8192
#define HH 1024
#define SS 256
#define KK 1024

// Finite in f32 AND bf16; strictly below any real score (see R3 post-mortem).
#define MASKED_SCORE (-1.0e38f)

typedef _Float16 half8 __attribute__((ext_vector_type(8)));
typedef float f32x4 __attribute__((ext_vector_type(4)));

// ---------------------------------------------------------------------------
// Prep: W' = gamma ⊙ w1 split to fp16 hi/lo in MFMA B-fragment order:
// element (s,k) -> [(colgrp*32 + ks)*512 + lane*8 + j], colgrp=s>>4, ks=k>>5,
// lane=((k>>3)&3)*16 + (s&15), j=k&7. u[s]=Σ γ w1; vb[s]=Σ β w1 + b1.
// ---------------------------------------------------------------------------
__global__ __launch_bounds__(256) void tbv9_prep(
    const float* __restrict__ gamma,
    const float* __restrict__ beta,
    const float* __restrict__ w1,
    const float* __restrict__ b1,
    _Float16* __restrict__ whT_sw,
    _Float16* __restrict__ wlT_sw,
    float* __restrict__ u,
    float* __restrict__ vb)
{
    const int s = blockIdx.x;
    const int tid = threadIdx.x;
    const int ctg = s >> 4;
    double ud = 0.0, vd = 0.0;
#pragma unroll
    for (int i = 0; i < 4; ++i) {
        const int k = tid * 4 + i;
        const float wv = gamma[k] * w1[(size_t)k * SS + s];
        const _Float16 hh = (_Float16)wv;
        const _Float16 hl = (_Float16)(wv - (float)hh);
        const size_t idx = ((size_t)(ctg * 32 + (k >> 5)) * 512)
                         + (((k >> 3) & 3) * 16 + (s & 15)) * 8 + (k & 7);
        whT_sw[idx] = hh;
        wlT_sw[idx] = hl;
        ud += (double)wv;
        vd += (double)beta[k] * (double)w1[(size_t)k * SS + s];
    }
#pragma unroll
    for (int off = 32; off; off >>= 1) {
        ud += __shfl_xor(ud, off, 64);
        vd += __shfl_xor(vd, off, 64);
    }
    __shared__ double su[4], sv[4];
    if ((tid & 63) == 0) { su[tid >> 6] = ud; sv[tid >> 6] = vd; }
    __syncthreads();
    if (tid == 0) {
        u[s]  = (float)(su[0] + su[1] + su[2] + su[3]);
        vb[s] = (float)(sv[0] + sv[1] + sv[2] + sv[3] + (double)b1[s]);
    }
}

// ---------------------------------------------------------------------------
// v9 scorer: 256 rows/block, 512 thr (8 waves = 2 row-halves x 4 col-quads).
// BK=64 dbuf LDS (fp16 hi/lo, XOR-swizzled). Grid = 256 = 1 block/CU.
// K-chunks processed in per-block staggered order (c + blockIdx) & 15 so the
// chip's HBM reads spread over all column offsets (channel balance).
// Per-acc MFMA chain identical per k-step to v5-v8 (ah·bh -> al·bh -> ah·bl).
// ---------------------------------------------------------------------------
__global__ __launch_bounds__(512, 2) void tbv9_scorer(
    const float* __restrict__ tokens,
    const _Float16* __restrict__ whT_sw,
    const _Float16* __restrict__ wlT_sw,
    const float* __restrict__ u,
    const float* __restrict__ vb,
    const float* __restrict__ w2,
    const float* __restrict__ b2,
    const int* __restrict__ mask,
    float* __restrict__ scores_out)
{
    __shared__ _Float16 Ah[2][256 * 64];
    __shared__ _Float16 Al[2][256 * 64];
    __shared__ float rs_s[256], m2_s[256];
    __shared__ float pl[4][256];

    const int tid  = threadIdx.x;
    const int lane = tid & 63;
    const int wid  = tid >> 6;
    const int wr   = wid >> 2;          // row-half 0/1
    const int wc   = wid & 3;           // col-quad 0..3
    const int r0   = blockIdx.x * 256;
    const int c0   = blockIdx.x & 15;   // per-block chunk stagger

    const int srow  = tid >> 1;         // 2 threads per row
    const int scolf = (tid & 1) * 32;   // 32 consecutive floats each
    const float* srcbase = tokens + (size_t)(r0 + srow) * HH + scolf;

    double s_acc = 0.0, ss_acc = 0.0;

    f32x4 acc[8][4];
#pragma unroll
    for (int rt = 0; rt < 8; ++rt)
#pragma unroll
        for (int ct = 0; ct < 4; ++ct) acc[rt][ct] = (f32x4){0.f, 0.f, 0.f, 0.f};

    const int arow = lane & 15;
    const int kgrp = (lane >> 4) * 8;
    const int swz  = (srow & 7) << 3;

    // convert 32 staged floats -> fp16 hi/lo + LN stats + swizzled LDS store
    auto convert_store = [&](const float4* rr, int buf) {
        half8 hh[4], hl[4];
#pragma unroll
        for (int jj = 0; jj < 8; ++jj) {
            const float4 v = rr[jj];
#pragma unroll
            for (int e = 0; e < 4; ++e) {
                const float x = (e == 0) ? v.x : (e == 1) ? v.y : (e == 2) ? v.z : v.w;
                const int j = jj * 4 + e;
                s_acc  += (double)x;
                ss_acc += (double)x * (double)x;
                const _Float16 h = (_Float16)x;
                hh[j >> 3][j & 7] = h;
                hl[j >> 3][j & 7] = (_Float16)(x - (float)h);
            }
        }
#pragma unroll
        for (int j = 0; j < 4; ++j) {
            const int idx = srow * 64 + ((scolf + j * 8) ^ swz);
            *reinterpret_cast<half8*>(&Ah[buf][idx]) = hh[j];
            *reinterpret_cast<half8*>(&Al[buf][idx]) = hl[j];
        }
    };

    // one K=32 MFMA step on absolute chunk cc
    auto do_kstep = [&](int buf, int cc, int k0) {
        half8 bh[4], bl[4];
#pragma unroll
        for (int ct = 0; ct < 4; ++ct) {
            const size_t base = ((size_t)((wc * 4 + ct) * 32 + cc * 2 + k0) * 512)
                              + lane * 8;
            bh[ct] = *reinterpret_cast<const half8*>(&whT_sw[base]);
            bl[ct] = *reinterpret_cast<const half8*>(&wlT_sw[base]);
        }
#pragma unroll
        for (int rt = 0; rt < 8; ++rt) {
            const int row = wr * 128 + rt * 16 + arow;
            const int idx = row * 64 + ((k0 * 32 + kgrp) ^ ((row & 7) << 3));
            const half8 ah = *reinterpret_cast<const half8*>(&Ah[buf][idx]);
            const half8 al = *reinterpret_cast<const half8*>(&Al[buf][idx]);
#pragma unroll
            for (int ct = 0; ct < 4; ++ct)
                acc[rt][ct] = __builtin_amdgcn_mfma_f32_16x16x32_f16(
                    ah, bh[ct], acc[rt][ct], 0, 0, 0);
#pragma unroll
            for (int ct = 0; ct < 4; ++ct)
                acc[rt][ct] = __builtin_amdgcn_mfma_f32_16x16x32_f16(
                    al, bh[ct], acc[rt][ct], 0, 0, 0);
#pragma unroll
            for (int ct = 0; ct < 4; ++ct)
                acc[rt][ct] = __builtin_amdgcn_mfma_f32_16x16x32_f16(
                    ah, bl[ct], acc[rt][ct], 0, 0, 0);
        }
    };

    // prologue: stage chunk c0 into buf 0
    {
        float4 r[8];
        const float* s0 = srcbase + c0 * 64;
#pragma unroll
        for (int j = 0; j < 8; ++j)
            r[j] = *reinterpret_cast<const float4*>(s0 + j * 4);
        convert_store(r, 0);
    }
    __syncthreads();

    for (int c = 0; c < 16; ++c) {
        const int cur = c & 1;
        const int cc  = (c + c0) & 15;        // this iteration's chunk
        float4 r2[8];
        if (c < 15) {
            const int ccn = (c + 1 + c0) & 15;
            const float* s2 = srcbase + ccn * 64;
#pragma unroll
            for (int j = 0; j < 8; ++j)
                r2[j] = *reinterpret_cast<const float4*>(s2 + j * 4);
        }
        do_kstep(cur, cc, 0);
        if (c < 15) convert_store(r2, cur ^ 1);   // writes OTHER buffer
        do_kstep(cur, cc, 1);
        __syncthreads();
    }

    // ---- LN stats finalize (2 threads per row) ----
    s_acc  += __shfl_xor(s_acc, 1, 64);
    ss_acc += __shfl_xor(ss_acc, 1, 64);
    if ((tid & 1) == 0) {
        const double mu  = s_acc * (1.0 / HH);
        const double var = ss_acc * (1.0 / HH) - mu * mu;
        const double rs  = 1.0 / sqrt(var + 1e-5);
        rs_s[srow] = (float)rs;
        m2_s[srow] = (float)(-mu * rs);
    }
    __syncthreads();

    // ---- epilogue (fp32): h = rs*G + m2*u + vb; relu; dot w2 ----
    float p[8][4];
#pragma unroll
    for (int rt = 0; rt < 8; ++rt)
#pragma unroll
        for (int q = 0; q < 4; ++q) p[rt][q] = 0.f;
#pragma unroll
    for (int ct = 0; ct < 4; ++ct) {
        const int col = wc * 64 + ct * 16 + arow;
        const float uc  = u[col];
        const float vbc = vb[col];
        const float w2c = w2[col];
#pragma unroll
        for (int rt = 0; rt < 8; ++rt)
#pragma unroll
            for (int q = 0; q < 4; ++q) {
                const int row = wr * 128 + rt * 16 + (lane >> 4) * 4 + q;
                const float h = rs_s[row] * acc[rt][ct][q] + m2_s[row] * uc + vbc;
                p[rt][q] += (h > 0.f ? h : 0.f) * w2c;
            }
    }
#pragma unroll
    for (int off = 8; off; off >>= 1)
#pragma unroll
        for (int rt = 0; rt < 8; ++rt)
#pragma unroll
            for (int q = 0; q < 4; ++q)
                p[rt][q] += __shfl_xor(p[rt][q], off, 64);
    if ((lane & 15) == 0)
#pragma unroll
        for (int rt = 0; rt < 8; ++rt)
#pragma unroll
            for (int q = 0; q < 4; ++q)
                pl[wc][wr * 128 + rt * 16 + (lane >> 4) * 4 + q] = p[rt][q];
    __syncthreads();

    if (tid < 256) {
        const size_t tok = (size_t)r0 + tid;
        float scf = pl[0][tid] + pl[1][tid] + pl[2][tid] + pl[3][tid]
                  + b2[0];
        if (mask[tok] == 0) scf = MASKED_SCORE;
        scores_out[tok] = scf;
    }
}

// ---------------------------------------------------------------------------
// Fallback fp64 scorer (only if ws too small for W' tables).
// ---------------------------------------------------------------------------
__global__ __launch_bounds__(256) void tbv9_scorer_fp64(
    const float* __restrict__ tokens,
    const float* __restrict__ gamma,
    const float* __restrict__ beta,
    const float* __restrict__ w1,
    const float* __restrict__ b1,
    const float* __restrict__ w2,
    const float* __restrict__ b2,
    const int* __restrict__ mask,
    float* __restrict__ scores_out)
{
    __shared__ float xs[16][HH];
    const int tid = threadIdx.x;
    const size_t tok0 = (size_t)blockIdx.x * 16;
    {
        const float4* src = reinterpret_cast<const float4*>(tokens + tok0 * HH);
        float4* dst = reinterpret_cast<float4*>(&xs[0][0]);
#pragma unroll
        for (int i = 0; i < (16 * HH / 4) / 256; ++i)
            dst[tid + i * 256] = src[tid + i * 256];
    }
    __syncthreads();
    {
        const int row = tid >> 4, l16 = tid & 15;
        double s = 0.0, ss = 0.0;
        for (int h = l16; h < HH; h += 16) {
            const double v = (double)xs[row][h];
            s += v; ss += v * v;
        }
#pragma unroll
        for (int off = 8; off; off >>= 1) {
            s += __shfl_xor(s, off, 64); ss += __shfl_xor(ss, off, 64);
        }
        const double mu = s / HH, var = ss / HH - mu * mu;
        const double rs = 1.0 / sqrt(var + 1e-5);
        for (int h = l16; h < HH; h += 16)
            xs[row][h] = (float)(((double)xs[row][h] - mu) * rs * (double)gamma[h]
                                 + (double)beta[h]);
    }
    __syncthreads();
    const int lane = tid & 63, wv_ = tid >> 6;
    double acc[4][4];
#pragma unroll
    for (int i = 0; i < 4; ++i)
#pragma unroll
        for (int c = 0; c < 4; ++c) acc[i][c] = 0.0;
    for (int h = 0; h < HH; ++h) {
        const float w0 = w1[(size_t)h * SS + lane];
        const float wc1 = w1[(size_t)h * SS + 64 + lane];
        const float wc2 = w1[(size_t)h * SS + 128 + lane];
        const float wc3 = w1[(size_t)h * SS + 192 + lane];
#pragma unroll
        for (int ii = 0; ii < 4; ++ii) {
            const double x0 = (double)xs[wv_ * 4 + ii][h];
            acc[ii][0] += x0 * (double)w0;  acc[ii][1] += x0 * (double)wc1;
            acc[ii][2] += x0 * (double)wc2; acc[ii][3] += x0 * (double)wc3;
        }
    }
    const double b2v = (double)b2[0];
#pragma unroll
    for (int ii = 0; ii < 4; ++ii) {
        double p = 0.0;
#pragma unroll
        for (int c = 0; c < 4; ++c) {
            const int scol = c * 64 + lane;
            double hv = acc[ii][c] + (double)b1[scol];
            hv = hv > 0.0 ? hv : 0.0;
            p += hv * (double)w2[scol];
        }
#pragma unroll
        for (int off = 32; off; off >>= 1) p += __shfl_xor(p, off, 64);
        if (lane == 0) {
            const size_t tok = tok0 + (size_t)wv_ * 4 + ii;
            float scf = (float)(p + b2v);
            if (mask[tok] == 0) scf = MASKED_SCORE;
            scores_out[tok] = scf;
        }
    }
}

// ---------------------------------------------------------------------------
// Top-k: per-batch bitonic sort of composite keys.
// ---------------------------------------------------------------------------
__global__ __launch_bounds__(1024) void tbv9_topk(
    const float* __restrict__ scores,
    const int* __restrict__ mask,
    float* __restrict__ idx_out,
    float* __restrict__ selmask_out)
{
    __shared__ unsigned long long k[NN];
    const int b = blockIdx.x, tid = threadIdx.x;
    for (int i = tid; i < NN; i += 1024) {
        const unsigned int uu = __float_as_uint(scores[(size_t)b * NN + i]);
        const unsigned int ord = (uu & 0x80000000u) ? ~uu : (uu | 0x80000000u);
        k[i] = ((unsigned long long)ord << 32) |
               (unsigned long long)(unsigned int)(NN - 1 - i);
    }
    __syncthreads();
    for (int kk = 2; kk <= NN; kk <<= 1) {
        for (int j = kk >> 1; j > 0; j >>= 1) {
            for (int p = tid; p < NN / 2; p += 1024) {
                const int i1 = 2 * p - (p & (j - 1));
                const int i2 = i1 + j;
                const unsigned long long a = k[i1], c = k[i2];
                const bool up = (i1 & kk) != 0;
                const bool sw = up ? (a > c) : (a < c);
                if (sw) { k[i1] = c; k[i2] = a; }
            }
            __syncthreads();
        }
    }
    for (int j = tid; j < KK; j += 1024) {
        const int n = (NN - 1) - (int)(k[j] & 0xFFFFFFFFull);
        const int m = mask[(size_t)b * NN + n] ? 1 : 0;
        idx_out[(size_t)b * KK + j]     = (float)n;
        selmask_out[(size_t)b * KK + j] = (float)m;
    }
}

// ---------------------------------------------------------------------------
// Gather.
// ---------------------------------------------------------------------------
__global__ __launch_bounds__(256) void tbv9_gather(
    const float* __restrict__ tokens,
    const float* __restrict__ idx_out,
    const int* __restrict__ mask,
    float* __restrict__ gathered)
{
    const int bj = blockIdx.x;
    const int b  = bj >> 10;
    const int n  = (int)idx_out[bj];
    const int m  = mask[(size_t)b * NN + n];
    const float4* src = reinterpret_cast<const float4*>(tokens + ((size_t)b * NN + n) * HH);
    float4* dst = reinterpret_cast<float4*>(gathered + (size_t)bj * HH);
    float4 v = src[threadIdx.x];
    if (!m) v = make_float4(0.f, 0.f, 0.f, 0.f);
    dst[threadIdx.x] = v;
}

// ---------------------------------------------------------------------------
extern "C" void kernel_launch(void* const* d_in, const int* in_sizes, int n_in,
                              void* d_out, int out_size, void* d_ws, size_t ws_size,
                              hipStream_t stream)
{
    const float* tokens = (const float*)d_in[0];
    const float* gamma  = (const float*)d_in[1];
    const float* beta   = (const float*)d_in[2];
    const float* w1     = (const float*)d_in[3];
    const float* b1     = (const float*)d_in[4];
    const float* w2     = (const float*)d_in[5];
    const float* b2     = (const float*)d_in[6];
    const int*   mask   = (const int*)d_in[7];

    float* out      = (float*)d_out;
    float* gathered = out;                                   // B*K*H
    float* idx_out  = out + (size_t)BB * KK * HH;            // B*K
    float* scores   = idx_out + (size_t)BB * KK;             // B*N
    float* selmask  = scores + (size_t)BB * NN;              // B*K

    const size_t whT_bytes = (size_t)SS * HH * sizeof(_Float16);   // 512KB
    const size_t need = 2 * whT_bytes + 2 * SS * sizeof(float);

    if (ws_size >= need) {
        _Float16* whT_sw = (_Float16*)d_ws;
        _Float16* wlT_sw = (_Float16*)((char*)d_ws + whT_bytes);
        float* u  = (float*)((char*)d_ws + 2 * whT_bytes);
        float* vbp = u + SS;
        hipLaunchKernelGGL(tbv9_prep, dim3(SS), dim3(256), 0, stream,
                           gamma, beta, w1, b1, whT_sw, wlT_sw, u, vbp);
        hipLaunchKernelGGL(tbv9_scorer, dim3(BB * NN / 256), dim3(512), 0, stream,
                           tokens, whT_sw, wlT_sw, u, vbp, w2, b2, mask, scores);
    } else {
        hipLaunchKernelGGL(tbv9_scorer_fp64, dim3(BB * NN / 16), dim3(256), 0, stream,
                           tokens, gamma, beta, w1, b1, w2, b2, mask, scores);
    }
    hipLaunchKernelGGL(tbv9_topk, dim3(BB), dim3(1024), 0, stream,
                       scores, mask, idx_out, selmask);
    hipLaunchKernelGGL(tbv9_gather, dim3(BB * KK), dim3(256), 0, stream,
                       tokens, idx_out, mask, gathered);
}

// Round 10
// 194.123 us; speedup vs baseline: 1.5957x; 1.0668x over previous
//
#include <hip/hip_runtime.h>
#include <hip/hip_bf16.h>
#include <math.h>
#include <stdint.h>

// TokenBottleneck v10 — spill-free scorer (lean staging, fp32 stats,
// interleaved B) + split top-k (slice sort + candidate sort).
#define BB 8
#define NN 8192
#define HH 1024
#define SS 256
#define KK 1024

// Finite in f32 AND bf16; strictly below any real score (see R3 post-mortem).
#define MASKED_SCORE (-1.0e38f)

typedef _Float16 half8 __attribute__((ext_vector_type(8)));
typedef float f32x4 __attribute__((ext_vector_type(4)));

// ---------------------------------------------------------------------------
// Prep: W' = gamma ⊙ w1 split fp16 hi/lo, INTERLEAVED fragment order:
// element (s,k): f=(s>>4)*32+(k>>5), lane=((k>>3)&3)*16+(s&15), j=k&7;
// hi at wB[f*1024 + lane*16 + j], lo at +8 (32B contiguous per lane).
// u[s]=Σ γ w1; vb[s]=Σ β w1 + b1.
// ---------------------------------------------------------------------------
__global__ __launch_bounds__(256) void tbv10_prep(
    const float* __restrict__ gamma,
    const float* __restrict__ beta,
    const float* __restrict__ w1,
    const float* __restrict__ b1,
    _Float16* __restrict__ wB,
    float* __restrict__ u,
    float* __restrict__ vb)
{
    const int s = blockIdx.x;
    const int tid = threadIdx.x;
    const int fbase = (s >> 4) * 32;
    double ud = 0.0, vd = 0.0;
#pragma unroll
    for (int i = 0; i < 4; ++i) {
        const int k = tid * 4 + i;
        const float wv = gamma[k] * w1[(size_t)k * SS + s];
        const _Float16 hh = (_Float16)wv;
        const _Float16 hl = (_Float16)(wv - (float)hh);
        const int f    = fbase + (k >> 5);
        const int lane = ((k >> 3) & 3) * 16 + (s & 15);
        const size_t idx = (size_t)f * 1024 + lane * 16 + (k & 7);
        wB[idx]     = hh;
        wB[idx + 8] = hl;
        ud += (double)wv;
        vd += (double)beta[k] * (double)w1[(size_t)k * SS + s];
    }
#pragma unroll
    for (int off = 32; off; off >>= 1) {
        ud += __shfl_xor(ud, off, 64);
        vd += __shfl_xor(vd, off, 64);
    }
    __shared__ double su[4], sv[4];
    if ((tid & 63) == 0) { su[tid >> 6] = ud; sv[tid >> 6] = vd; }
    __syncthreads();
    if (tid == 0) {
        u[s]  = (float)(su[0] + su[1] + su[2] + su[3]);
        vb[s] = (float)(sv[0] + sv[1] + sv[2] + sv[3] + (double)b1[s]);
    }
}

// ---------------------------------------------------------------------------
// v10 scorer: BM=256, 512 thr (8 waves = 2 row-halves x 4 col-quads), BK=64
// dbuf LDS, per-block chunk stagger. Lean staging: 2 prefetch halves of
// 4xfloat4; fp32 LN stats; B hi/lo interleaved (one 32B load region).
// ---------------------------------------------------------------------------
__global__ __launch_bounds__(512, 2) void tbv10_scorer(
    const float* __restrict__ tokens,
    const _Float16* __restrict__ wB,
    const float* __restrict__ u,
    const float* __restrict__ vb,
    const float* __restrict__ w2,
    const float* __restrict__ b2,
    const int* __restrict__ mask,
    float* __restrict__ scores_out)
{
    __shared__ _Float16 Ah[2][256 * 64];
    __shared__ _Float16 Al[2][256 * 64];
    __shared__ float rs_s[256], m2_s[256];
    __shared__ float pl[4][256];

    const int tid  = threadIdx.x;
    const int lane = tid & 63;
    const int wid  = tid >> 6;
    const int wr   = wid >> 2;
    const int wc   = wid & 3;
    const int r0   = blockIdx.x * 256;
    const int c0   = blockIdx.x & 15;

    const int srow  = tid >> 1;
    const int scolf = (tid & 1) * 32;
    const float* srcbase = tokens + (size_t)(r0 + srow) * HH + scolf;

    float s_acc = 0.f, ss_acc = 0.f;

    f32x4 acc[8][4];
#pragma unroll
    for (int rt = 0; rt < 8; ++rt)
#pragma unroll
        for (int ct = 0; ct < 4; ++ct) acc[rt][ct] = (f32x4){0.f, 0.f, 0.f, 0.f};

    const int arow = lane & 15;
    const int kgrp = (lane >> 4) * 8;
    const int swz  = (srow & 7) << 3;

    // convert 16 floats (4 x float4) -> fp16 hi/lo + stats + swizzled store
    auto convert_store16 = [&](const float4* rr, int halfsel, int buf) {
        half8 hh[2], hl[2];
#pragma unroll
        for (int jj = 0; jj < 4; ++jj) {
            const float4 v = rr[jj];
#pragma unroll
            for (int e = 0; e < 4; ++e) {
                const float x = (e == 0) ? v.x : (e == 1) ? v.y : (e == 2) ? v.z : v.w;
                const int j = jj * 4 + e;
                s_acc  += x;
                ss_acc += x * x;
                const _Float16 h = (_Float16)x;
                hh[j >> 3][j & 7] = h;
                hl[j >> 3][j & 7] = (_Float16)(x - (float)h);
            }
        }
        const int colb = scolf + halfsel * 16;
#pragma unroll
        for (int t = 0; t < 2; ++t) {
            const int idx = srow * 64 + ((colb + t * 8) ^ swz);
            *reinterpret_cast<half8*>(&Ah[buf][idx]) = hh[t];
            *reinterpret_cast<half8*>(&Al[buf][idx]) = hl[t];
        }
    };

    auto do_kstep = [&](int buf, int cc, int k0) {
        half8 bh[4], bl[4];
#pragma unroll
        for (int ct = 0; ct < 4; ++ct) {
            const size_t base = ((size_t)((wc * 4 + ct) * 32 + cc * 2 + k0) * 1024)
                              + lane * 16;
            bh[ct] = *reinterpret_cast<const half8*>(&wB[base]);
            bl[ct] = *reinterpret_cast<const half8*>(&wB[base + 8]);
        }
#pragma unroll
        for (int rt = 0; rt < 8; ++rt) {
            const int row = wr * 128 + rt * 16 + arow;
            const int idx = row * 64 + ((k0 * 32 + kgrp) ^ ((row & 7) << 3));
            const half8 ah = *reinterpret_cast<const half8*>(&Ah[buf][idx]);
            const half8 al = *reinterpret_cast<const half8*>(&Al[buf][idx]);
#pragma unroll
            for (int ct = 0; ct < 4; ++ct)
                acc[rt][ct] = __builtin_amdgcn_mfma_f32_16x16x32_f16(
                    ah, bh[ct], acc[rt][ct], 0, 0, 0);
#pragma unroll
            for (int ct = 0; ct < 4; ++ct)
                acc[rt][ct] = __builtin_amdgcn_mfma_f32_16x16x32_f16(
                    al, bh[ct], acc[rt][ct], 0, 0, 0);
#pragma unroll
            for (int ct = 0; ct < 4; ++ct)
                acc[rt][ct] = __builtin_amdgcn_mfma_f32_16x16x32_f16(
                    ah, bl[ct], acc[rt][ct], 0, 0, 0);
        }
    };

    // prologue: stage chunk c0 -> buf 0
    {
        const float* s0 = srcbase + c0 * 64;
        float4 ra[4], rb[4];
#pragma unroll
        for (int j = 0; j < 4; ++j) ra[j] = *reinterpret_cast<const float4*>(s0 + j * 4);
#pragma unroll
        for (int j = 0; j < 4; ++j) rb[j] = *reinterpret_cast<const float4*>(s0 + 16 + j * 4);
        convert_store16(ra, 0, 0);
        convert_store16(rb, 1, 0);
    }
    __syncthreads();

    for (int c = 0; c < 16; ++c) {
        const int cur = c & 1;
        const int cc  = (c + c0) & 15;
        const float* s2 = srcbase + (size_t)((c + 1 + c0) & 15) * 64;
        float4 ra[4];
        if (c < 15) {
#pragma unroll
            for (int j = 0; j < 4; ++j)
                ra[j] = *reinterpret_cast<const float4*>(s2 + j * 4);
        }
        do_kstep(cur, cc, 0);
        float4 rb[4];
        if (c < 15) {
            convert_store16(ra, 0, cur ^ 1);
#pragma unroll
            for (int j = 0; j < 4; ++j)
                rb[j] = *reinterpret_cast<const float4*>(s2 + 16 + j * 4);
        }
        do_kstep(cur, cc, 1);
        if (c < 15) convert_store16(rb, 1, cur ^ 1);
        __syncthreads();
    }

    // ---- LN stats finalize (2 threads per row) ----
    s_acc  += __shfl_xor(s_acc, 1, 64);
    ss_acc += __shfl_xor(ss_acc, 1, 64);
    if ((tid & 1) == 0) {
        const double mu  = (double)s_acc * (1.0 / HH);
        const double var = (double)ss_acc * (1.0 / HH) - mu * mu;
        const double rs  = 1.0 / sqrt(var + 1e-5);
        rs_s[srow] = (float)rs;
        m2_s[srow] = (float)(-mu * rs);
    }
    __syncthreads();

    // ---- epilogue (fp32): h = rs*G + m2*u + vb; relu; dot w2 ----
    float p[8][4];
#pragma unroll
    for (int rt = 0; rt < 8; ++rt)
#pragma unroll
        for (int q = 0; q < 4; ++q) p[rt][q] = 0.f;
#pragma unroll
    for (int ct = 0; ct < 4; ++ct) {
        const int col = wc * 64 + ct * 16 + arow;
        const float uc  = u[col];
        const float vbc = vb[col];
        const float w2c = w2[col];
#pragma unroll
        for (int rt = 0; rt < 8; ++rt)
#pragma unroll
            for (int q = 0; q < 4; ++q) {
                const int row = wr * 128 + rt * 16 + (lane >> 4) * 4 + q;
                const float h = rs_s[row] * acc[rt][ct][q] + m2_s[row] * uc + vbc;
                p[rt][q] += (h > 0.f ? h : 0.f) * w2c;
            }
    }
#pragma unroll
    for (int off = 8; off; off >>= 1)
#pragma unroll
        for (int rt = 0; rt < 8; ++rt)
#pragma unroll
            for (int q = 0; q < 4; ++q)
                p[rt][q] += __shfl_xor(p[rt][q], off, 64);
    if ((lane & 15) == 0)
#pragma unroll
        for (int rt = 0; rt < 8; ++rt)
#pragma unroll
            for (int q = 0; q < 4; ++q)
                pl[wc][wr * 128 + rt * 16 + (lane >> 4) * 4 + q] = p[rt][q];
    __syncthreads();

    if (tid < 256) {
        const size_t tok = (size_t)r0 + tid;
        float scf = pl[0][tid] + pl[1][tid] + pl[2][tid] + pl[3][tid] + b2[0];
        if (mask[tok] == 0) scf = MASKED_SCORE;
        scores_out[tok] = scf;
    }
}

// ---------------------------------------------------------------------------
// Top-k stage A: per (batch, slice-of-2048) descending bitonic sort; emit the
// slice's top-1024 candidate keys. Grid: BB*4 x 1024 threads.
// ---------------------------------------------------------------------------
__global__ __launch_bounds__(1024) void tbv10_sortslice(
    const float* __restrict__ scores,
    unsigned long long* __restrict__ cand)
{
    __shared__ unsigned long long k[2048];
    const int b = blockIdx.x >> 2, sl = blockIdx.x & 3;
    const int tid = threadIdx.x;
    const int nbase = sl * 2048;
#pragma unroll
    for (int t = 0; t < 2; ++t) {
        const int i = tid + t * 1024;
        const int n = nbase + i;
        const unsigned int uu = __float_as_uint(scores[(size_t)b * NN + n]);
        const unsigned int ord = (uu & 0x80000000u) ? ~uu : (uu | 0x80000000u);
        k[i] = ((unsigned long long)ord << 32) |
               (unsigned long long)(unsigned int)(NN - 1 - n);
    }
    __syncthreads();
    for (int kk = 2; kk <= 2048; kk <<= 1) {
        for (int j = kk >> 1; j > 0; j >>= 1) {
            const int p = tid;
            const int i1 = 2 * p - (p & (j - 1));
            const int i2 = i1 + j;
            const unsigned long long a = k[i1], c = k[i2];
            const bool up = (i1 & kk) != 0;
            const bool sw = up ? (a > c) : (a < c);
            if (sw) { k[i1] = c; k[i2] = a; }
            __syncthreads();
        }
    }
    cand[(size_t)b * 4096 + sl * 1024 + tid] = k[tid];
}

// ---------------------------------------------------------------------------
// Top-k stage B: per batch sort the 4096 candidates desc; emit top-1024
// indices + selmask. Grid: BB x 1024 threads.
// ---------------------------------------------------------------------------
__global__ __launch_bounds__(1024) void tbv10_topk4k(
    const unsigned long long* __restrict__ cand,
    const int* __restrict__ mask,
    float* __restrict__ idx_out,
    float* __restrict__ selmask_out)
{
    __shared__ unsigned long long k[4096];
    const int b = blockIdx.x, tid = threadIdx.x;
#pragma unroll
    for (int t = 0; t < 4; ++t)
        k[tid + t * 1024] = cand[(size_t)b * 4096 + tid + t * 1024];
    __syncthreads();
    for (int kk = 2; kk <= 4096; kk <<= 1) {
        for (int j = kk >> 1; j > 0; j >>= 1) {
            for (int p = tid; p < 2048; p += 1024) {
                const int i1 = 2 * p - (p & (j - 1));
                const int i2 = i1 + j;
                const unsigned long long a = k[i1], c = k[i2];
                const bool up = (i1 & kk) != 0;
                const bool sw = up ? (a > c) : (a < c);
                if (sw) { k[i1] = c; k[i2] = a; }
            }
            __syncthreads();
        }
    }
    const int n = (NN - 1) - (int)(k[tid] & 0xFFFFFFFFull);
    const int m = mask[(size_t)b * NN + n] ? 1 : 0;
    idx_out[(size_t)b * KK + tid]     = (float)n;
    selmask_out[(size_t)b * KK + tid] = (float)m;
}

// ---------------------------------------------------------------------------
// Monolithic top-k fallback (ws-small path).
// ---------------------------------------------------------------------------
__global__ __launch_bounds__(1024) void tbv10_topk_mono(
    const float* __restrict__ scores,
    const int* __restrict__ mask,
    float* __restrict__ idx_out,
    float* __restrict__ selmask_out)
{
    __shared__ unsigned long long k[NN];
    const int b = blockIdx.x, tid = threadIdx.x;
    for (int i = tid; i < NN; i += 1024) {
        const unsigned int uu = __float_as_uint(scores[(size_t)b * NN + i]);
        const unsigned int ord = (uu & 0x80000000u) ? ~uu : (uu | 0x80000000u);
        k[i] = ((unsigned long long)ord << 32) |
               (unsigned long long)(unsigned int)(NN - 1 - i);
    }
    __syncthreads();
    for (int kk = 2; kk <= NN; kk <<= 1) {
        for (int j = kk >> 1; j > 0; j >>= 1) {
            for (int p = tid; p < NN / 2; p += 1024) {
                const int i1 = 2 * p - (p & (j - 1));
                const int i2 = i1 + j;
                const unsigned long long a = k[i1], c = k[i2];
                const bool up = (i1 & kk) != 0;
                const bool sw = up ? (a > c) : (a < c);
                if (sw) { k[i1] = c; k[i2] = a; }
            }
            __syncthreads();
        }
    }
    for (int j = tid; j < KK; j += 1024) {
        const int n = (NN - 1) - (int)(k[j] & 0xFFFFFFFFull);
        const int m = mask[(size_t)b * NN + n] ? 1 : 0;
        idx_out[(size_t)b * KK + j]     = (float)n;
        selmask_out[(size_t)b * KK + j] = (float)m;
    }
}

// ---------------------------------------------------------------------------
// Fallback fp64 scorer (only if ws too small for tables).
// ---------------------------------------------------------------------------
__global__ __launch_bounds__(256) void tbv10_scorer_fp64(
    const float* __restrict__ tokens,
    const float* __restrict__ gamma,
    const float* __restrict__ beta,
    const float* __restrict__ w1,
    const float* __restrict__ b1,
    const float* __restrict__ w2,
    const float* __restrict__ b2,
    const int* __restrict__ mask,
    float* __restrict__ scores_out)
{
    __shared__ float xs[16][HH];
    const int tid = threadIdx.x;
    const size_t tok0 = (size_t)blockIdx.x * 16;
    {
        const float4* src = reinterpret_cast<const float4*>(tokens + tok0 * HH);
        float4* dst = reinterpret_cast<float4*>(&xs[0][0]);
#pragma unroll
        for (int i = 0; i < (16 * HH / 4) / 256; ++i)
            dst[tid + i * 256] = src[tid + i * 256];
    }
    __syncthreads();
    {
        const int row = tid >> 4, l16 = tid & 15;
        double s = 0.0, ss = 0.0;
        for (int h = l16; h < HH; h += 16) {
            const double v = (double)xs[row][h];
            s += v; ss += v * v;
        }
#pragma unroll
        for (int off = 8; off; off >>= 1) {
            s += __shfl_xor(s, off, 64); ss += __shfl_xor(ss, off, 64);
        }
        const double mu = s / HH, var = ss / HH - mu * mu;
        const double rs = 1.0 / sqrt(var + 1e-5);
        for (int h = l16; h < HH; h += 16)
            xs[row][h] = (float)(((double)xs[row][h] - mu) * rs * (double)gamma[h]
                                 + (double)beta[h]);
    }
    __syncthreads();
    const int lane = tid & 63, wv_ = tid >> 6;
    double acc[4][4];
#pragma unroll
    for (int i = 0; i < 4; ++i)
#pragma unroll
        for (int c = 0; c < 4; ++c) acc[i][c] = 0.0;
    for (int h = 0; h < HH; ++h) {
        const float w0 = w1[(size_t)h * SS + lane];
        const float wc1 = w1[(size_t)h * SS + 64 + lane];
        const float wc2 = w1[(size_t)h * SS + 128 + lane];
        const float wc3 = w1[(size_t)h * SS + 192 + lane];
#pragma unroll
        for (int ii = 0; ii < 4; ++ii) {
            const double x0 = (double)xs[wv_ * 4 + ii][h];
            acc[ii][0] += x0 * (double)w0;  acc[ii][1] += x0 * (double)wc1;
            acc[ii][2] += x0 * (double)wc2; acc[ii][3] += x0 * (double)wc3;
        }
    }
    const double b2v = (double)b2[0];
#pragma unroll
    for (int ii = 0; ii < 4; ++ii) {
        double p = 0.0;
#pragma unroll
        for (int c = 0; c < 4; ++c) {
            const int scol = c * 64 + lane;
            double hv = acc[ii][c] + (double)b1[scol];
            hv = hv > 0.0 ? hv : 0.0;
            p += hv * (double)w2[scol];
        }
#pragma unroll
        for (int off = 32; off; off >>= 1) p += __shfl_xor(p, off, 64);
        if (lane == 0) {
            const size_t tok = tok0 + (size_t)wv_ * 4 + ii;
            float scf = (float)(p + b2v);
            if (mask[tok] == 0) scf = MASKED_SCORE;
            scores_out[tok] = scf;
        }
    }
}

// ---------------------------------------------------------------------------
// Gather.
// ---------------------------------------------------------------------------
__global__ __launch_bounds__(256) void tbv10_gather(
    const float* __restrict__ tokens,
    const float* __restrict__ idx_out,
    const int* __restrict__ mask,
    float* __restrict__ gathered)
{
    const int bj = blockIdx.x;
    const int b  = bj >> 10;
    const int n  = (int)idx_out[bj];
    const int m  = mask[(size_t)b * NN + n];
    const float4* src = reinterpret_cast<const float4*>(tokens + ((size_t)b * NN + n) * HH);
    float4* dst = reinterpret_cast<float4*>(gathered + (size_t)bj * HH);
    float4 v = src[threadIdx.x];
    if (!m) v = make_float4(0.f, 0.f, 0.f, 0.f);
    dst[threadIdx.x] = v;
}

// ---------------------------------------------------------------------------
extern "C" void kernel_launch(void* const* d_in, const int* in_sizes, int n_in,
                              void* d_out, int out_size, void* d_ws, size_t ws_size,
                              hipStream_t stream)
{
    const float* tokens = (const float*)d_in[0];
    const float* gamma  = (const float*)d_in[1];
    const float* beta   = (const float*)d_in[2];
    const float* w1     = (const float*)d_in[3];
    const float* b1     = (const float*)d_in[4];
    const float* w2     = (const float*)d_in[5];
    const float* b2     = (const float*)d_in[6];
    const int*   mask   = (const int*)d_in[7];

    float* out      = (float*)d_out;
    float* gathered = out;                                   // B*K*H
    float* idx_out  = out + (size_t)BB * KK * HH;            // B*K
    float* scores   = idx_out + (size_t)BB * KK;             // B*N
    float* selmask  = scores + (size_t)BB * NN;              // B*K

    const size_t wB_bytes   = (size_t)SS * HH * 2 * sizeof(_Float16);   // 1MB
    const size_t uvb_bytes  = 2 * SS * sizeof(float);
    const size_t cand_bytes = (size_t)BB * 4096 * sizeof(unsigned long long);
    const size_t need = wB_bytes + uvb_bytes + cand_bytes;

    if (ws_size >= need) {
        _Float16* wB = (_Float16*)d_ws;
        float* u   = (float*)((char*)d_ws + wB_bytes);
        float* vbp = u + SS;
        unsigned long long* cand =
            (unsigned long long*)((char*)d_ws + wB_bytes + uvb_bytes);

        hipLaunchKernelGGL(tbv10_prep, dim3(SS), dim3(256), 0, stream,
                           gamma, beta, w1, b1, wB, u, vbp);
        hipLaunchKernelGGL(tbv10_scorer, dim3(BB * NN / 256), dim3(512), 0, stream,
                           tokens, wB, u, vbp, w2, b2, mask, scores);
        hipLaunchKernelGGL(tbv10_sortslice, dim3(BB * 4), dim3(1024), 0, stream,
                           scores, cand);
        hipLaunchKernelGGL(tbv10_topk4k, dim3(BB), dim3(1024), 0, stream,
                           cand, mask, idx_out, selmask);
    } else {
        hipLaunchKernelGGL(tbv10_scorer_fp64, dim3(BB * NN / 16), dim3(256), 0, stream,
                           tokens, gamma, beta, w1, b1, w2, b2, mask, scores);
        hipLaunchKernelGGL(tbv10_topk_mono, dim3(BB), dim3(1024), 0, stream,
                           scores, mask, idx_out, selmask);
    }
    hipLaunchKernelGGL(tbv10_gather, dim3(BB * KK), dim3(256), 0, stream,
                       tokens, idx_out, mask, gathered);
}